// Round 1
// baseline (1100.200 us; speedup 1.0000x reference)
//
#include <hip/hip_runtime.h>
#include <hip/hip_bf16.h>
#include <cstdio>

// ---------------------------------------------------------------------------
// DinomalyBlock forward: B=8, N=4096, C=768, H=12, D=64, BN=384
// Pipeline:
//   wq/wp/wd/wu -> bf16 transposed [Nc][K]
//   ln1 = LN(x,g1,b1)                          (bf16)
//   qkv = ln1 @ Wqkv + b ; elu+1 on q,k        (bf16, MFMA GEMM)
//   kv[b,h] = sum_n k^T v ; ksum = sum_n k     (fp32 atomics)
//   attn = (q @ kv) / (q . ksum + 1e-6)        (bf16, [B,N,C] layout)
//   x2 = x + attn @ Wproj + b                  (fp32, in d_out)
//   r  = LN(x2,g2,b2)                          (bf16)
//   h  = gelu_exact(r @ Wdown + b)             (bf16)
//   s  = r + h @ Wup + b                       (fp32, in d_out)
//   out= LN(s,g3,b3)                           (fp32, in-place d_out)
// ---------------------------------------------------------------------------

typedef __attribute__((ext_vector_type(8))) short short8;
typedef __attribute__((ext_vector_type(4))) float floatx4;

__device__ __forceinline__ float bf2f(unsigned short u) {
    return __uint_as_float(((unsigned int)u) << 16);
}
__device__ __forceinline__ unsigned short f2bf(float f) {
    __hip_bfloat16 h = __float2bfloat16(f);
    return *reinterpret_cast<unsigned short*>(&h);
}

// ---------------- weight transpose + fp32->bf16 ----------------------------
// W: [K][Nc] fp32 row-major  ->  Wt: [Nc][K] bf16
__global__ __launch_bounds__(256) void transpose_bf16(
    const float* __restrict__ w, unsigned short* __restrict__ wt, int K, int Nc)
{
    __shared__ float tile[32][33];
    int kb = blockIdx.x * 32, nb = blockIdx.y * 32;
    int tx = threadIdx.x, ty = threadIdx.y;   // block (32,8)
    #pragma unroll
    for (int i = 0; i < 32; i += 8)
        tile[ty + i][tx] = w[(size_t)(kb + ty + i) * Nc + nb + tx];
    __syncthreads();
    #pragma unroll
    for (int i = 0; i < 32; i += 8)
        wt[(size_t)(nb + ty + i) * K + kb + tx] = f2bf(tile[tx][ty + i]);
}

// ---------------- LayerNorm over C=768 -------------------------------------
template<bool OBF16>
__global__ __launch_bounds__(256) void ln_kernel(
    const float* __restrict__ in, const float* __restrict__ gw,
    const float* __restrict__ bw, void* __restrict__ outp)
{
    int row = blockIdx.x;
    const float* x = in + (size_t)row * 768;
    int t = threadIdx.x;
    float v0 = x[t], v1 = x[t + 256], v2 = x[t + 512];
    float s = v0 + v1 + v2;
    float ss = v0 * v0 + v1 * v1 + v2 * v2;
    #pragma unroll
    for (int o = 32; o > 0; o >>= 1) {
        s += __shfl_down(s, o);
        ss += __shfl_down(ss, o);
    }
    __shared__ float red[8];
    int wave = t >> 6, lane = t & 63;
    if (lane == 0) { red[wave] = s; red[4 + wave] = ss; }
    __syncthreads();
    if (t == 0) {
        float S = red[0] + red[1] + red[2] + red[3];
        float SS = red[4] + red[5] + red[6] + red[7];
        float mu = S * (1.0f / 768.0f);
        float var = SS * (1.0f / 768.0f) - mu * mu;
        red[0] = mu;
        red[1] = rsqrtf(var + 1e-5f);
    }
    __syncthreads();
    float mu = red[0], rstd = red[1];
    #pragma unroll
    for (int e = 0; e < 3; e++) {
        int c = t + e * 256;
        float v = (e == 0) ? v0 : (e == 1) ? v1 : v2;
        float y = (v - mu) * rstd * gw[c] + bw[c];
        if (OBF16) ((unsigned short*)outp)[(size_t)row * 768 + c] = f2bf(y);
        else       ((float*)outp)[(size_t)row * 768 + c] = y;
    }
}

// ---------------- MFMA GEMM: out = A[M,K](bf16) @ Wt[Nc,K]^T + bias --------
// MODE 0: qkv     -> bf16 out, elu+1 on cols < 1536
// MODE 1: proj    -> fp32 out, + fp32 residual
// MODE 2: down    -> bf16 out, exact GELU
// MODE 3: up      -> fp32 out, + bf16 residual
template<int MODE>
__global__ __launch_bounds__(256, 2) void gemm_kernel(
    const unsigned short* __restrict__ A,
    const unsigned short* __restrict__ Wt,
    const float* __restrict__ bias,
    const void* __restrict__ resv,
    void* __restrict__ outv,
    int M, int K, int Nc)
{
    __shared__ __align__(16) unsigned short As[128][40];
    __shared__ __align__(16) unsigned short Bs[128][40];
    const int row0 = blockIdx.x * 128;
    const int col0 = blockIdx.y * 128;
    const int t = threadIdx.x;
    const int lane = t & 63;
    const int wave = t >> 6;
    const int wm = (wave >> 1) * 64;
    const int wn = (wave & 1) * 64;
    const int ar = t >> 1;            // staging row (0..127)
    const int akc = (t & 1) * 16;     // staging k-offset
    const int frow = lane & 15;
    const int fk = (lane >> 4) * 8;

    floatx4 acc[4][4];
    #pragma unroll
    for (int i = 0; i < 4; i++)
        #pragma unroll
        for (int j = 0; j < 4; j++)
            acc[i][j] = (floatx4){0.f, 0.f, 0.f, 0.f};

    for (int k0 = 0; k0 < K; k0 += 32) {
        const unsigned short* as = A + (size_t)(row0 + ar) * K + k0 + akc;
        const unsigned short* bs = Wt + (size_t)(col0 + ar) * K + k0 + akc;
        uint4 av0 = *(const uint4*)(as);
        uint4 av1 = *(const uint4*)(as + 8);
        uint4 bv0 = *(const uint4*)(bs);
        uint4 bv1 = *(const uint4*)(bs + 8);
        __syncthreads();
        *(uint4*)&As[ar][akc] = av0;
        *(uint4*)&As[ar][akc + 8] = av1;
        *(uint4*)&Bs[ar][akc] = bv0;
        *(uint4*)&Bs[ar][akc + 8] = bv1;
        __syncthreads();
        short8 af[4], bf[4];
        #pragma unroll
        for (int i = 0; i < 4; i++) af[i] = *(const short8*)&As[wm + i * 16 + frow][fk];
        #pragma unroll
        for (int j = 0; j < 4; j++) bf[j] = *(const short8*)&Bs[wn + j * 16 + frow][fk];
        #pragma unroll
        for (int i = 0; i < 4; i++)
            #pragma unroll
            for (int j = 0; j < 4; j++)
                acc[i][j] = __builtin_amdgcn_mfma_f32_16x16x32_bf16(
                    af[i], bf[j], acc[i][j], 0, 0, 0);
    }

    #pragma unroll
    for (int i = 0; i < 4; i++) {
        #pragma unroll
        for (int j = 0; j < 4; j++) {
            int col = col0 + wn + j * 16 + (lane & 15);
            float bcol = bias[col];
            #pragma unroll
            for (int rr = 0; rr < 4; rr++) {
                int row = row0 + wm + i * 16 + (lane >> 4) * 4 + rr;
                float v = acc[i][j][rr] + bcol;
                size_t idx = (size_t)row * Nc + col;
                if (MODE == 0) {
                    if (col < 1536) v = (v > 0.f) ? (v + 1.f) : expf(v);
                    ((unsigned short*)outv)[idx] = f2bf(v);
                } else if (MODE == 1) {
                    v += ((const float*)resv)[idx];
                    ((float*)outv)[idx] = v;
                } else if (MODE == 2) {
                    v = 0.5f * v * (1.0f + erff(v * 0.70710678118654752f));
                    ((unsigned short*)outv)[idx] = f2bf(v);
                } else {
                    v += bf2f(((const unsigned short*)resv)[idx]);
                    ((float*)outv)[idx] = v;
                }
            }
        }
    }
}

// ---------------- linear attention: kv accumulation ------------------------
// grid = B*H*8 blocks (512 rows each); kvbuf[b*H+h] is 65x64 fp32:
//   rows 0..63 = kv[d][v], row 64 = ksum[d]
__global__ __launch_bounds__(256) void kv_accum(
    const unsigned short* __restrict__ qkv, float* __restrict__ kvbuf)
{
    int blk = blockIdx.x;
    int chunk = blk & 7;
    int bh = blk >> 3;
    int b = bh / 12, h = bh % 12;
    int n0 = chunk * 512;
    int t = threadIdx.x;
    int d = t & 63, g = t >> 6;        // g uniform per wave
    __shared__ float kl[16][64];
    __shared__ float vl[16][64];
    float kv[16];
    #pragma unroll
    for (int j = 0; j < 16; j++) kv[j] = 0.f;
    float ks = 0.f;

    int e0 = t * 8;
    int sr = e0 >> 7;          // staging row 0..15
    int sc = e0 & 127;         // staging col 0..120 (mult of 8)
    for (int batch = 0; batch < 512; batch += 16) {
        size_t base = ((size_t)b * 4096 + n0 + batch + sr) * 2304;
        int col = (sc < 64) ? (768 + h * 64 + sc) : (1536 + h * 64 + (sc - 64));
        const unsigned short* src = qkv + base + col;
        float* dst = (sc < 64) ? &kl[sr][sc] : &vl[sr][sc - 64];
        #pragma unroll
        for (int i = 0; i < 8; i++) dst[i] = bf2f(src[i]);
        __syncthreads();
        #pragma unroll 4
        for (int r2 = 0; r2 < 16; r2++) {
            float kd = kl[r2][d];
            if (g == 0) ks += kd;
            #pragma unroll
            for (int j = 0; j < 16; j++) kv[j] += kd * vl[r2][g * 16 + j];
        }
        __syncthreads();
    }
    float* dstg = kvbuf + (size_t)bh * 4160;
    #pragma unroll
    for (int j = 0; j < 16; j++) atomicAdd(&dstg[d * 64 + g * 16 + j], kv[j]);
    if (g == 0) atomicAdd(&dstg[4096 + d], ks);
}

// ---------------- linear attention: apply + normalize ----------------------
// grid = B*H*256 blocks (16 rows each); writes attn in [B,N,C] layout (bf16)
__global__ __launch_bounds__(256) void attn_apply(
    const unsigned short* __restrict__ qkv, const float* __restrict__ kvbuf,
    unsigned short* __restrict__ attnC)
{
    int blk = blockIdx.x;
    int nchunk = blk & 255;
    int bh = blk >> 8;
    int b = bh / 12, h = bh % 12;
    int n0 = nchunk * 16;
    int t = threadIdx.x;
    __shared__ float kvl[4160];
    __shared__ float ql[16][64];
    const float* src = kvbuf + (size_t)bh * 4160;
    for (int i = t; i < 4160; i += 256) kvl[i] = src[i];
    {
        int r = t >> 4, c0 = (t & 15) * 4;
        size_t base = ((size_t)b * 4096 + n0 + r) * 2304 + h * 64 + c0;
        #pragma unroll
        for (int i = 0; i < 4; i++) ql[r][c0 + i] = bf2f(qkv[base + i]);
    }
    __syncthreads();
    int r = t >> 4;
    int v0 = t & 15;
    float o[4] = {0.f, 0.f, 0.f, 0.f};
    float norm = 0.f;
    #pragma unroll 4
    for (int d2 = 0; d2 < 64; d2++) {
        float qv = ql[r][d2];
        norm += qv * kvl[4096 + d2];
        #pragma unroll
        for (int jj = 0; jj < 4; jj++) o[jj] += qv * kvl[d2 * 64 + v0 + jj * 16];
    }
    float inv = 1.0f / (norm + 1e-6f);
    size_t obase = ((size_t)b * 4096 + n0 + r) * 768 + h * 64 + v0;
    #pragma unroll
    for (int jj = 0; jj < 4; jj++) attnC[obase + jj * 16] = f2bf(o[jj] * inv);
}

// ---------------------------------------------------------------------------
extern "C" void kernel_launch(void* const* d_in, const int* in_sizes, int n_in,
                              void* d_out, int out_size, void* d_ws, size_t ws_size,
                              hipStream_t stream)
{
    const float* x      = (const float*)d_in[0];
    const float* w_qkv  = (const float*)d_in[1];
    const float* b_qkv  = (const float*)d_in[2];
    const float* w_proj = (const float*)d_in[3];
    const float* b_proj = (const float*)d_in[4];
    const float* g1     = (const float*)d_in[5];
    const float* be1    = (const float*)d_in[6];
    const float* g2     = (const float*)d_in[7];
    const float* be2    = (const float*)d_in[8];
    const float* w_down = (const float*)d_in[9];
    const float* b_down = (const float*)d_in[10];
    const float* w_up   = (const float*)d_in[11];
    const float* b_up   = (const float*)d_in[12];
    const float* g3     = (const float*)d_in[13];
    const float* be3    = (const float*)d_in[14];

    char* p = (char*)d_ws;
    auto take = [&](size_t b) { char* q = p; p += (b + 255) & ~(size_t)255; return q; };
    unsigned short* wtq  = (unsigned short*)take((size_t)2304 * 768 * 2);
    unsigned short* wtp  = (unsigned short*)take((size_t)768 * 768 * 2);
    unsigned short* wtd  = (unsigned short*)take((size_t)384 * 768 * 2);
    unsigned short* wtu  = (unsigned short*)take((size_t)768 * 384 * 2);
    unsigned short* bufA = (unsigned short*)take((size_t)32768 * 768 * 2);  // ln1 / attnC
    unsigned short* qkvb = (unsigned short*)take((size_t)32768 * 2304 * 2); // qkv ; later r
    float*          kvb  = (float*)take((size_t)96 * 4160 * 4);
    unsigned short* hbuf = (unsigned short*)take((size_t)32768 * 384 * 2);
    unsigned short* rbuf = qkvb;  // alias: r overwrites qkv (qkv dead after attn_apply)

    size_t needed = (size_t)(p - (char*)d_ws);
    if (needed > ws_size)
        fprintf(stderr, "WARNING: ws too small: need %zu have %zu\n", needed, ws_size);

    dim3 tb(32, 8);
    transpose_bf16<<<dim3(24, 72), tb, 0, stream>>>(w_qkv, wtq, 768, 2304);
    transpose_bf16<<<dim3(24, 24), tb, 0, stream>>>(w_proj, wtp, 768, 768);
    transpose_bf16<<<dim3(24, 12), tb, 0, stream>>>(w_down, wtd, 768, 384);
    transpose_bf16<<<dim3(12, 24), tb, 0, stream>>>(w_up, wtu, 384, 768);
    hipMemsetAsync(kvb, 0, (size_t)96 * 4160 * 4, stream);

    // ln1 (bf16)
    ln_kernel<true><<<32768, 256, 0, stream>>>(x, g1, be1, bufA);
    // qkv GEMM + elu+1 on q,k
    gemm_kernel<0><<<dim3(256, 18), 256, 0, stream>>>(bufA, wtq, b_qkv, nullptr, qkvb,
                                                      32768, 768, 2304);
    // attention
    kv_accum<<<768, 256, 0, stream>>>(qkvb, kvb);
    attn_apply<<<24576, 256, 0, stream>>>(qkvb, kvb, bufA);
    // proj + residual(x) -> x2 in d_out
    gemm_kernel<1><<<dim3(256, 6), 256, 0, stream>>>(bufA, wtp, b_proj, x, d_out,
                                                     32768, 768, 768);
    // ln2 -> r (bf16)
    ln_kernel<true><<<32768, 256, 0, stream>>>((const float*)d_out, g2, be2, rbuf);
    // down + gelu -> h (bf16)
    gemm_kernel<2><<<dim3(256, 3), 256, 0, stream>>>(rbuf, wtd, b_down, nullptr, hbuf,
                                                     32768, 768, 384);
    // up + residual(r) -> s in d_out
    gemm_kernel<3><<<dim3(256, 6), 256, 0, stream>>>(hbuf, wtu, b_up, rbuf, d_out,
                                                     32768, 384, 768);
    // ln3 in-place on d_out (fp32)
    ln_kernel<false><<<32768, 256, 0, stream>>>((const float*)d_out, g3, be3, (float*)d_out);
}

// Round 2
// 727.431 us; speedup vs baseline: 1.5124x; 1.5124x over previous
//
#include <hip/hip_runtime.h>
#include <hip/hip_bf16.h>
#include <cstdio>

// ---------------------------------------------------------------------------
// DinomalyBlock forward: B=8, N=4096, C=768, H=12, D=64, BN=384
// ---------------------------------------------------------------------------

typedef __attribute__((ext_vector_type(8))) short short8;
typedef __attribute__((ext_vector_type(4))) float floatx4;

__device__ __forceinline__ float bf2f(unsigned short u) {
    return __uint_as_float(((unsigned int)u) << 16);
}
__device__ __forceinline__ unsigned short f2bf(float f) {
    __hip_bfloat16 h = __float2bfloat16(f);
    return *reinterpret_cast<unsigned short*>(&h);
}

// async global->LDS, 16B per lane; LDS dest = wave-uniform base + lane*16
__device__ __forceinline__ void async_copy16(const unsigned short* g, unsigned short* l) {
    __builtin_amdgcn_global_load_lds(
        (const __attribute__((address_space(1))) unsigned int*)g,
        (__attribute__((address_space(3))) unsigned int*)l, 16, 0, 0);
}

// ---------------- weight transpose + fp32->bf16 ----------------------------
__global__ __launch_bounds__(256) void transpose_bf16(
    const float* __restrict__ w, unsigned short* __restrict__ wt, int K, int Nc)
{
    __shared__ float tile[32][33];
    int kb = blockIdx.x * 32, nb = blockIdx.y * 32;
    int tx = threadIdx.x, ty = threadIdx.y;   // block (32,8)
    #pragma unroll
    for (int i = 0; i < 32; i += 8)
        tile[ty + i][tx] = w[(size_t)(kb + ty + i) * Nc + nb + tx];
    __syncthreads();
    #pragma unroll
    for (int i = 0; i < 32; i += 8)
        wt[(size_t)(nb + ty + i) * K + kb + tx] = f2bf(tile[tx][ty + i]);
}

// ---------------- LayerNorm over C=768 -------------------------------------
template<bool OBF16>
__global__ __launch_bounds__(256) void ln_kernel(
    const float* __restrict__ in, const float* __restrict__ gw,
    const float* __restrict__ bw, void* __restrict__ outp)
{
    int row = blockIdx.x;
    const float* x = in + (size_t)row * 768;
    int t = threadIdx.x;
    float v0 = x[t], v1 = x[t + 256], v2 = x[t + 512];
    float s = v0 + v1 + v2;
    float ss = v0 * v0 + v1 * v1 + v2 * v2;
    #pragma unroll
    for (int o = 32; o > 0; o >>= 1) {
        s += __shfl_down(s, o);
        ss += __shfl_down(ss, o);
    }
    __shared__ float red[8];
    int wave = t >> 6, lane = t & 63;
    if (lane == 0) { red[wave] = s; red[4 + wave] = ss; }
    __syncthreads();
    if (t == 0) {
        float S = red[0] + red[1] + red[2] + red[3];
        float SS = red[4] + red[5] + red[6] + red[7];
        float mu = S * (1.0f / 768.0f);
        float var = SS * (1.0f / 768.0f) - mu * mu;
        red[0] = mu;
        red[1] = rsqrtf(var + 1e-5f);
    }
    __syncthreads();
    float mu = red[0], rstd = red[1];
    #pragma unroll
    for (int e = 0; e < 3; e++) {
        int c = t + e * 256;
        float v = (e == 0) ? v0 : (e == 1) ? v1 : v2;
        float y = (v - mu) * rstd * gw[c] + bw[c];
        if (OBF16) ((unsigned short*)outp)[(size_t)row * 768 + c] = f2bf(y);
        else       ((float*)outp)[(size_t)row * 768 + c] = y;
    }
}

// ---------------- MFMA GEMM: out = A[M,K](bf16) @ Wt[Nc,K]^T + bias --------
// MODE 0: qkv -> bf16, elu+1 on cols<1536 | 1: +fp32 res -> fp32
// MODE 2: exact GELU -> bf16              | 3: +bf16 res -> fp32
template<int MODE>
__global__ __launch_bounds__(256, 2) void gemm_kernel(
    const unsigned short* __restrict__ A,
    const unsigned short* __restrict__ Wt,
    const float* __restrict__ bias,
    const void* __restrict__ resv,
    void* __restrict__ outv,
    int M, int K, int Nc)
{
    __shared__ __align__(16) unsigned short As[128][32];
    __shared__ __align__(16) unsigned short Bs[128][32];
    const int row0 = blockIdx.x * 128;
    const int col0 = blockIdx.y * 128;
    const int t = threadIdx.x;
    const int lane = t & 63;
    const int wave = t >> 6;
    const int wm = (wave >> 1) * 64;
    const int wn = (wave & 1) * 64;
    const int srow = t >> 2;          // 0..63
    const int skc = (t & 3) * 8;      // k-offset within 32
    const int frow = lane & 15;
    const int fk = (lane >> 4) * 8;

    floatx4 acc[4][4];
    #pragma unroll
    for (int i = 0; i < 4; i++)
        #pragma unroll
        for (int j = 0; j < 4; j++)
            acc[i][j] = (floatx4){0.f, 0.f, 0.f, 0.f};

    for (int k0 = 0; k0 < K; k0 += 32) {
        __syncthreads();   // previous iter's frag reads done
        async_copy16(A  + (size_t)(row0 + srow) * K + k0 + skc,       &As[wave * 16][0]);
        async_copy16(A  + (size_t)(row0 + 64 + srow) * K + k0 + skc,  &As[64 + wave * 16][0]);
        async_copy16(Wt + (size_t)(col0 + srow) * K + k0 + skc,       &Bs[wave * 16][0]);
        async_copy16(Wt + (size_t)(col0 + 64 + srow) * K + k0 + skc,  &Bs[64 + wave * 16][0]);
        __syncthreads();   // drains vmcnt
        short8 af[4], bf[4];
        #pragma unroll
        for (int i = 0; i < 4; i++) af[i] = *(const short8*)&As[wm + i * 16 + frow][fk];
        #pragma unroll
        for (int j = 0; j < 4; j++) bf[j] = *(const short8*)&Bs[wn + j * 16 + frow][fk];
        #pragma unroll
        for (int i = 0; i < 4; i++)
            #pragma unroll
            for (int j = 0; j < 4; j++)
                acc[i][j] = __builtin_amdgcn_mfma_f32_16x16x32_bf16(
                    af[i], bf[j], acc[i][j], 0, 0, 0);
    }

    #pragma unroll
    for (int i = 0; i < 4; i++) {
        #pragma unroll
        for (int j = 0; j < 4; j++) {
            int col = col0 + wn + j * 16 + (lane & 15);
            float bcol = bias[col];
            #pragma unroll
            for (int rr = 0; rr < 4; rr++) {
                int row = row0 + wm + i * 16 + (lane >> 4) * 4 + rr;
                float v = acc[i][j][rr] + bcol;
                size_t idx = (size_t)row * Nc + col;
                if (MODE == 0) {
                    if (col < 1536) v = (v > 0.f) ? (v + 1.f) : expf(v);
                    ((unsigned short*)outv)[idx] = f2bf(v);
                } else if (MODE == 1) {
                    v += ((const float*)resv)[idx];
                    ((float*)outv)[idx] = v;
                } else if (MODE == 2) {
                    v = 0.5f * v * (1.0f + erff(v * 0.70710678118654752f));
                    ((unsigned short*)outv)[idx] = f2bf(v);
                } else {
                    v += bf2f(((const unsigned short*)resv)[idx]);
                    ((float*)outv)[idx] = v;
                }
            }
        }
    }
}

// ---------------- linear attention: kv accumulation ------------------------
// grid = B*H*8 (512 rows each); kvbuf[bh] 4160 fp32: [e*64+d] = kvT, [4096+d]=ksum
__global__ __launch_bounds__(256) void kv_accum(
    const unsigned short* __restrict__ qkv, float* __restrict__ kvbuf)
{
    int blk = blockIdx.x;
    int chunk = blk & 7;
    int bh = blk >> 3;
    int b = bh / 12, h = bh % 12;
    int n0 = chunk * 512;
    int t = threadIdx.x;
    int d = t & 63, g = t >> 6;
    __shared__ float kl[2][32][68];
    __shared__ float vl[2][32][68];
    float kv[16];
    #pragma unroll
    for (int j = 0; j < 16; j++) kv[j] = 0.f;
    float ks = 0.f;

    int sr = t >> 3;            // staging row 0..31
    int c16 = (t & 7) * 16;     // 0..112
    bool isk = c16 < 64;
    int cc = isk ? c16 : c16 - 64;
    const unsigned short* gbase =
        qkv + (size_t)(b * 4096 + n0 + sr) * 2304 + (isk ? 768 : 1536) + h * 64 + cc;
    uint4 r0, r1;
    auto loadg = [&](int nb) {
        const uint4* s = (const uint4*)(gbase + (size_t)nb * 2304);
        r0 = s[0]; r1 = s[1];
    };
    auto storel = [&](int buf) {
        float* dst = isk ? &kl[buf][sr][cc] : &vl[buf][sr][cc];
        const unsigned short* u0 = (const unsigned short*)&r0;
        const unsigned short* u1 = (const unsigned short*)&r1;
        #pragma unroll
        for (int i = 0; i < 8; i++) dst[i] = bf2f(u0[i]);
        #pragma unroll
        for (int i = 0; i < 8; i++) dst[8 + i] = bf2f(u1[i]);
    };

    loadg(0);
    storel(0);
    __syncthreads();
    for (int c = 0; c < 16; c++) {
        if (c < 15) loadg((c + 1) * 32);
        int bsel = c & 1;
        #pragma unroll 8
        for (int r2 = 0; r2 < 32; r2++) {
            float kd = kl[bsel][r2][d];
            ks += kd;
            const float4* vv = (const float4*)&vl[bsel][r2][g * 16];
            float4 a0 = vv[0], a1 = vv[1], a2 = vv[2], a3 = vv[3];
            kv[0]  += kd * a0.x; kv[1]  += kd * a0.y; kv[2]  += kd * a0.z; kv[3]  += kd * a0.w;
            kv[4]  += kd * a1.x; kv[5]  += kd * a1.y; kv[6]  += kd * a1.z; kv[7]  += kd * a1.w;
            kv[8]  += kd * a2.x; kv[9]  += kd * a2.y; kv[10] += kd * a2.z; kv[11] += kd * a2.w;
            kv[12] += kd * a3.x; kv[13] += kd * a3.y; kv[14] += kd * a3.z; kv[15] += kd * a3.w;
        }
        if (c < 15) storel((c + 1) & 1);
        __syncthreads();
    }
    float* dstg = kvbuf + (size_t)bh * 4160;
    #pragma unroll
    for (int j = 0; j < 16; j++)
        atomicAdd(&dstg[(g * 16 + j) * 64 + d], kv[j]);   // transposed: [e][d]
    if (g == 0) atomicAdd(&dstg[4096 + d], ks);
}

// ---------------- linear attention: apply via MFMA -------------------------
// grid = B*H*32 (128 rows each). D[n][e] = sum_d q[n,d]*kvT[e,d]; 5th e-tile
// holds ksum row -> normalizer in col 64.
__global__ __launch_bounds__(256) void attn_apply(
    const unsigned short* __restrict__ qkv, const float* __restrict__ kvbuf,
    unsigned short* __restrict__ attnC)
{
    int blk = blockIdx.x;
    int nchunk = blk & 31;
    int bh = blk >> 5;
    int b = bh / 12, h = bh % 12;
    int n0 = nchunk * 128;
    int t = threadIdx.x;
    int lane = t & 63, wave = t >> 6;
    __shared__ __align__(16) unsigned short ql[128][72];
    __shared__ __align__(16) unsigned short Bs[80][72];

    {   // stage kvT (fp32->bf16) into Bs rows 0..63; ksum row 64; zeros 65..79
        const float* kvg = kvbuf + (size_t)bh * 4160;
        int e = t >> 2, d0 = (t & 3) * 16;
        const float4* src4 = (const float4*)(kvg + e * 64 + d0);
        #pragma unroll
        for (int i = 0; i < 4; i++) {
            float4 v = src4[i];
            unsigned long long pk = (unsigned long long)f2bf(v.x)
                | ((unsigned long long)f2bf(v.y) << 16)
                | ((unsigned long long)f2bf(v.z) << 32)
                | ((unsigned long long)f2bf(v.w) << 48);
            *(unsigned long long*)&Bs[e][d0 + i * 4] = pk;
        }
        if (t < 64) {
            Bs[64][t] = f2bf(kvg[4096 + t]);
            #pragma unroll
            for (int r = 65; r < 80; r++) Bs[r][t] = 0;
        }
    }
    {   // stage q rows (raw bf16 copy)
        int r = t >> 1, c0 = (t & 1) * 32;
        const uint4* src = (const uint4*)(qkv + (size_t)(b * 4096 + n0 + r) * 2304 + h * 64 + c0);
        uint4* dst = (uint4*)&ql[r][c0];
        #pragma unroll
        for (int i = 0; i < 4; i++) dst[i] = src[i];
    }
    __syncthreads();

    int frow = lane & 15, quad = lane >> 4;
    floatx4 acc[2][5];
    #pragma unroll
    for (int it = 0; it < 2; it++)
        #pragma unroll
        for (int jt = 0; jt < 5; jt++)
            acc[it][jt] = (floatx4){0.f, 0.f, 0.f, 0.f};

    #pragma unroll
    for (int ks = 0; ks < 2; ks++) {
        int fk = ks * 32 + quad * 8;
        short8 a0 = *(const short8*)&ql[wave * 32 + frow][fk];
        short8 a1 = *(const short8*)&ql[wave * 32 + 16 + frow][fk];
        #pragma unroll
        for (int jt = 0; jt < 5; jt++) {
            short8 bb = *(const short8*)&Bs[jt * 16 + frow][fk];
            acc[0][jt] = __builtin_amdgcn_mfma_f32_16x16x32_bf16(a0, bb, acc[0][jt], 0, 0, 0);
            acc[1][jt] = __builtin_amdgcn_mfma_f32_16x16x32_bf16(a1, bb, acc[1][jt], 0, 0, 0);
        }
    }

    #pragma unroll
    for (int it = 0; it < 2; it++) {
        #pragma unroll
        for (int rr = 0; rr < 4; rr++) {
            float nv = __shfl(acc[it][4][rr], (lane & 48));   // norm from col 0 of tile 4
            float inv = 1.0f / (nv + 1e-6f);
            int row = n0 + wave * 32 + it * 16 + quad * 4 + rr;
            size_t obase = (size_t)(b * 4096 + row) * 768 + h * 64;
            #pragma unroll
            for (int jt = 0; jt < 4; jt++)
                attnC[obase + jt * 16 + frow] = f2bf(acc[it][jt][rr] * inv);
        }
    }
}

// ---------------------------------------------------------------------------
extern "C" void kernel_launch(void* const* d_in, const int* in_sizes, int n_in,
                              void* d_out, int out_size, void* d_ws, size_t ws_size,
                              hipStream_t stream)
{
    const float* x      = (const float*)d_in[0];
    const float* w_qkv  = (const float*)d_in[1];
    const float* b_qkv  = (const float*)d_in[2];
    const float* w_proj = (const float*)d_in[3];
    const float* b_proj = (const float*)d_in[4];
    const float* g1     = (const float*)d_in[5];
    const float* be1    = (const float*)d_in[6];
    const float* g2     = (const float*)d_in[7];
    const float* be2    = (const float*)d_in[8];
    const float* w_down = (const float*)d_in[9];
    const float* b_down = (const float*)d_in[10];
    const float* w_up   = (const float*)d_in[11];
    const float* b_up   = (const float*)d_in[12];
    const float* g3     = (const float*)d_in[13];
    const float* be3    = (const float*)d_in[14];

    char* p = (char*)d_ws;
    auto take = [&](size_t b) { char* q = p; p += (b + 255) & ~(size_t)255; return q; };
    unsigned short* wtq  = (unsigned short*)take((size_t)2304 * 768 * 2);
    unsigned short* wtp  = (unsigned short*)take((size_t)768 * 768 * 2);
    unsigned short* wtd  = (unsigned short*)take((size_t)384 * 768 * 2);
    unsigned short* wtu  = (unsigned short*)take((size_t)768 * 384 * 2);
    unsigned short* bufA = (unsigned short*)take((size_t)32768 * 768 * 2);  // ln1 / attnC
    unsigned short* qkvb = (unsigned short*)take((size_t)32768 * 2304 * 2); // qkv ; later r
    float*          kvb  = (float*)take((size_t)96 * 4160 * 4);
    unsigned short* hbuf = (unsigned short*)take((size_t)32768 * 384 * 2);
    unsigned short* rbuf = qkvb;  // alias: r overwrites qkv (qkv dead after attn_apply)

    size_t needed = (size_t)(p - (char*)d_ws);
    if (needed > ws_size)
        fprintf(stderr, "WARNING: ws too small: need %zu have %zu\n", needed, ws_size);

    dim3 tb(32, 8);
    transpose_bf16<<<dim3(24, 72), tb, 0, stream>>>(w_qkv, wtq, 768, 2304);
    transpose_bf16<<<dim3(24, 24), tb, 0, stream>>>(w_proj, wtp, 768, 768);
    transpose_bf16<<<dim3(24, 12), tb, 0, stream>>>(w_down, wtd, 768, 384);
    transpose_bf16<<<dim3(12, 24), tb, 0, stream>>>(w_up, wtu, 384, 768);
    hipMemsetAsync(kvb, 0, (size_t)96 * 4160 * 4, stream);

    ln_kernel<true><<<32768, 256, 0, stream>>>(x, g1, be1, bufA);
    gemm_kernel<0><<<dim3(256, 18), 256, 0, stream>>>(bufA, wtq, b_qkv, nullptr, qkvb,
                                                      32768, 768, 2304);
    kv_accum<<<768, 256, 0, stream>>>(qkvb, kvb);
    attn_apply<<<3072, 256, 0, stream>>>(qkvb, kvb, bufA);
    gemm_kernel<1><<<dim3(256, 6), 256, 0, stream>>>(bufA, wtp, b_proj, x, d_out,
                                                     32768, 768, 768);
    ln_kernel<true><<<32768, 256, 0, stream>>>((const float*)d_out, g2, be2, rbuf);
    gemm_kernel<2><<<dim3(256, 3), 256, 0, stream>>>(rbuf, wtd, b_down, nullptr, hbuf,
                                                     32768, 768, 384);
    gemm_kernel<3><<<dim3(256, 6), 256, 0, stream>>>(hbuf, wtu, b_up, rbuf, d_out,
                                                     32768, 384, 768);
    ln_kernel<false><<<32768, 256, 0, stream>>>((const float*)d_out, g3, be3, (float*)d_out);
}

// Round 3
// 698.192 us; speedup vs baseline: 1.5758x; 1.0419x over previous
//
#include <hip/hip_runtime.h>
#include <hip/hip_bf16.h>
#include <cstdio>

// ---------------------------------------------------------------------------
// DinomalyBlock forward: B=8, N=4096, C=768, H=12, D=64, BN=384
// ---------------------------------------------------------------------------

typedef __attribute__((ext_vector_type(8))) short short8;
typedef __attribute__((ext_vector_type(4))) float floatx4;

__device__ __forceinline__ float bf2f(unsigned short u) {
    return __uint_as_float(((unsigned int)u) << 16);
}
__device__ __forceinline__ unsigned short f2bf(float f) {
    __hip_bfloat16 h = __float2bfloat16(f);
    return *reinterpret_cast<unsigned short*>(&h);
}

// async global->LDS, 16B/lane; LDS dest = wave-uniform base + lane*16
__device__ __forceinline__ void async_copy16(const unsigned short* g, unsigned short* l) {
    __builtin_amdgcn_global_load_lds(
        (const __attribute__((address_space(1))) unsigned int*)g,
        (__attribute__((address_space(3))) unsigned int*)l, 16, 0, 0);
}

// ---------------- all weight transposes in one launch ----------------------
// W: [K][Nc] fp32 -> Wt: [Nc][K] bf16, 32x32 tiles
__global__ __launch_bounds__(256) void transpose_all(
    const float* __restrict__ wq, const float* __restrict__ wp,
    const float* __restrict__ wd, const float* __restrict__ wu,
    unsigned short* __restrict__ tq, unsigned short* __restrict__ tp,
    unsigned short* __restrict__ td, unsigned short* __restrict__ tu)
{
    int blk = blockIdx.x;
    const float* w; unsigned short* o; int K, Nc, tx32;
    if (blk < 1728)      { w = wq; o = tq; K = 768; Nc = 2304; tx32 = 24; }
    else if (blk < 2304) { w = wp; o = tp; K = 768; Nc = 768;  tx32 = 24; blk -= 1728; }
    else if (blk < 2592) { w = wd; o = td; K = 768; Nc = 384;  tx32 = 24; blk -= 2304; }
    else                 { w = wu; o = tu; K = 384; Nc = 768;  tx32 = 12; blk -= 2592; }
    int kb = (blk % tx32) * 32, nb = (blk / tx32) * 32;
    __shared__ float tile[32][33];
    int tx = threadIdx.x & 31, ty = threadIdx.x >> 5;   // 32x8
    #pragma unroll
    for (int i = 0; i < 32; i += 8)
        tile[ty + i][tx] = w[(size_t)(kb + ty + i) * Nc + nb + tx];
    __syncthreads();
    #pragma unroll
    for (int i = 0; i < 32; i += 8)
        o[(size_t)(nb + ty + i) * K + kb + tx] = f2bf(tile[tx][ty + i]);
}

// ---------------- LayerNorm over C=768, 384 threads ------------------------
template<bool OBF16>
__global__ __launch_bounds__(384) void ln_kernel(
    const float* __restrict__ in, const float* __restrict__ gw,
    const float* __restrict__ bw, void* __restrict__ outp)
{
    int row = blockIdx.x;
    int t = threadIdx.x;
    float2 xv = ((const float2*)(in + (size_t)row * 768))[t];
    float s = xv.x + xv.y;
    float ss = xv.x * xv.x + xv.y * xv.y;
    #pragma unroll
    for (int o = 32; o > 0; o >>= 1) {
        s += __shfl_down(s, o);
        ss += __shfl_down(ss, o);
    }
    __shared__ float red[14];
    int wave = t >> 6, lane = t & 63;
    if (lane == 0) { red[wave] = s; red[6 + wave] = ss; }
    __syncthreads();
    if (t == 0) {
        float S = 0.f, SS = 0.f;
        #pragma unroll
        for (int i = 0; i < 6; i++) { S += red[i]; SS += red[6 + i]; }
        float mu = S * (1.0f / 768.0f);
        float var = SS * (1.0f / 768.0f) - mu * mu;
        red[12] = mu;
        red[13] = rsqrtf(var + 1e-5f);
    }
    __syncthreads();
    float mu = red[12], rstd = red[13];
    float2 g = ((const float2*)gw)[t];
    float2 b = ((const float2*)bw)[t];
    float y0 = (xv.x - mu) * rstd * g.x + b.x;
    float y1 = (xv.y - mu) * rstd * g.y + b.y;
    if (OBF16) {
        unsigned int pk = (unsigned int)f2bf(y0) | ((unsigned int)f2bf(y1) << 16);
        ((unsigned int*)outp)[(size_t)row * 384 + t] = pk;
    } else {
        ((float2*)outp)[(size_t)row * 384 + t] = make_float2(y0, y1);
    }
}

// ---------------- fused residual add + LayerNorm ---------------------------
// s = bf16(y) + res ; out = LN(s)
template<bool RES_F32, bool OUT_F32>
__global__ __launch_bounds__(384) void add_ln_kernel(
    const unsigned short* __restrict__ y, const void* __restrict__ resv,
    const float* __restrict__ gw, const float* __restrict__ bw,
    void* __restrict__ outp)
{
    int row = blockIdx.x;
    int t = threadIdx.x;
    unsigned int yp = ((const unsigned int*)(y + (size_t)row * 768))[t];
    float a0 = bf2f((unsigned short)(yp & 0xffff));
    float a1 = bf2f((unsigned short)(yp >> 16));
    float r0, r1;
    if (RES_F32) {
        float2 rv = ((const float2*)((const float*)resv + (size_t)row * 768))[t];
        r0 = rv.x; r1 = rv.y;
    } else {
        unsigned int rp = ((const unsigned int*)((const unsigned short*)resv + (size_t)row * 768))[t];
        r0 = bf2f((unsigned short)(rp & 0xffff));
        r1 = bf2f((unsigned short)(rp >> 16));
    }
    float v0 = a0 + r0, v1 = a1 + r1;
    float s = v0 + v1;
    float ss = v0 * v0 + v1 * v1;
    #pragma unroll
    for (int o = 32; o > 0; o >>= 1) {
        s += __shfl_down(s, o);
        ss += __shfl_down(ss, o);
    }
    __shared__ float red[14];
    int wave = t >> 6, lane = t & 63;
    if (lane == 0) { red[wave] = s; red[6 + wave] = ss; }
    __syncthreads();
    if (t == 0) {
        float S = 0.f, SS = 0.f;
        #pragma unroll
        for (int i = 0; i < 6; i++) { S += red[i]; SS += red[6 + i]; }
        float mu = S * (1.0f / 768.0f);
        float var = SS * (1.0f / 768.0f) - mu * mu;
        red[12] = mu;
        red[13] = rsqrtf(var + 1e-5f);
    }
    __syncthreads();
    float mu = red[12], rstd = red[13];
    float2 g = ((const float2*)gw)[t];
    float2 b = ((const float2*)bw)[t];
    float y0 = (v0 - mu) * rstd * g.x + b.x;
    float y1 = (v1 - mu) * rstd * g.y + b.y;
    if (OUT_F32) {
        ((float2*)outp)[(size_t)row * 384 + t] = make_float2(y0, y1);
    } else {
        unsigned int pk = (unsigned int)f2bf(y0) | ((unsigned int)f2bf(y1) << 16);
        ((unsigned int*)outp)[(size_t)row * 384 + t] = pk;
    }
}

// ---------------- MFMA GEMM: out = A[M,K](bf16) @ Wt[Nc,K]^T + bias --------
// BK=64, XOR-swizzled LDS (phys_chunk = logical_chunk ^ (row&7)); bf16 out.
// MODE 0: elu+1 on cols<1536 (qkv) | 1: plain | 2: exact GELU
template<int MODE>
__global__ __launch_bounds__(256, 2) void gemm_kernel(
    const unsigned short* __restrict__ A,
    const unsigned short* __restrict__ Wt,
    const float* __restrict__ bias,
    unsigned short* __restrict__ outp,
    int M, int K, int Nc)
{
    __shared__ __align__(16) unsigned short As[128][64];
    __shared__ __align__(16) unsigned short Bs[128][64];
    const int row0 = blockIdx.x * 128;
    const int col0 = blockIdx.y * 128;
    const int t = threadIdx.x;
    const int lane = t & 63;
    const int wave = t >> 6;
    const int wm = (wave >> 1) * 64;
    const int wn = (wave & 1) * 64;
    const int frow = lane & 15;
    const int quad = lane >> 4;
    const int lrow = lane >> 3;                 // 0..7 within staging group
    const int lchunk = (lane & 7) ^ lrow;       // logical chunk this lane fetches

    floatx4 acc[4][4];
    #pragma unroll
    for (int i = 0; i < 4; i++)
        #pragma unroll
        for (int j = 0; j < 4; j++)
            acc[i][j] = (floatx4){0.f, 0.f, 0.f, 0.f};

    for (int k0 = 0; k0 < K; k0 += 64) {
        __syncthreads();   // previous iter's frag reads done
        #pragma unroll
        for (int q = 0; q < 4; q++) {
            int r = wave * 32 + q * 8 + lrow;
            async_copy16(A  + (size_t)(row0 + r) * K + k0 + lchunk * 8, &As[wave * 32 + q * 8][0]);
            async_copy16(Wt + (size_t)(col0 + r) * K + k0 + lchunk * 8, &Bs[wave * 32 + q * 8][0]);
        }
        __syncthreads();   // drains vmcnt
        #pragma unroll
        for (int ks = 0; ks < 2; ks++) {
            const int pc = ((ks * 4 + quad) ^ (frow & 7)) * 8;
            short8 af[4], bf4[4];
            #pragma unroll
            for (int i = 0; i < 4; i++) af[i] = *(const short8*)&As[wm + i * 16 + frow][pc];
            #pragma unroll
            for (int j = 0; j < 4; j++) bf4[j] = *(const short8*)&Bs[wn + j * 16 + frow][pc];
            #pragma unroll
            for (int i = 0; i < 4; i++)
                #pragma unroll
                for (int j = 0; j < 4; j++)
                    acc[i][j] = __builtin_amdgcn_mfma_f32_16x16x32_bf16(
                        af[i], bf4[j], acc[i][j], 0, 0, 0);
        }
    }

    #pragma unroll
    for (int i = 0; i < 4; i++) {
        #pragma unroll
        for (int j = 0; j < 4; j++) {
            int col = col0 + wn + j * 16 + frow;
            float bcol = bias[col];
            #pragma unroll
            for (int rr = 0; rr < 4; rr++) {
                int row = row0 + wm + i * 16 + quad * 4 + rr;
                float v = acc[i][j][rr] + bcol;
                if (MODE == 0) {
                    if (col < 1536) v = (v > 0.f) ? (v + 1.f) : expf(v);
                } else if (MODE == 2) {
                    v = 0.5f * v * (1.0f + erff(v * 0.70710678118654752f));
                }
                outp[(size_t)row * Nc + col] = f2bf(v);
            }
        }
    }
}

// ---------------- linear attention: kv accumulation ------------------------
// grid = B*H*8 (512 rows each); kvbuf[bh] 4160 fp32: [e*64+d]=kvT, [4096+d]=ksum
__global__ __launch_bounds__(256) void kv_accum(
    const unsigned short* __restrict__ qkv, float* __restrict__ kvbuf)
{
    int blk = blockIdx.x;
    int chunk = blk & 7;
    int bh = blk >> 3;
    int b = bh / 12, h = bh % 12;
    int n0 = chunk * 512;
    int t = threadIdx.x;
    int d = t & 63, g = t >> 6;
    __shared__ float kl[2][32][68];
    __shared__ float vl[2][32][68];
    float kv[16];
    #pragma unroll
    for (int j = 0; j < 16; j++) kv[j] = 0.f;
    float ks = 0.f;

    int sr = t >> 3;            // staging row 0..31
    int c16 = (t & 7) * 16;     // 0..112
    bool isk = c16 < 64;
    int cc = isk ? c16 : c16 - 64;
    const unsigned short* gbase =
        qkv + (size_t)(b * 4096 + n0 + sr) * 2304 + (isk ? 768 : 1536) + h * 64 + cc;
    uint4 r0, r1;
    auto loadg = [&](int nb) {
        const uint4* s = (const uint4*)(gbase + (size_t)nb * 2304);
        r0 = s[0]; r1 = s[1];
    };
    auto storel = [&](int buf) {
        float* dst = isk ? &kl[buf][sr][cc] : &vl[buf][sr][cc];
        const unsigned short* u0 = (const unsigned short*)&r0;
        const unsigned short* u1 = (const unsigned short*)&r1;
        #pragma unroll
        for (int i = 0; i < 8; i++) dst[i] = bf2f(u0[i]);
        #pragma unroll
        for (int i = 0; i < 8; i++) dst[8 + i] = bf2f(u1[i]);
    };

    loadg(0);
    storel(0);
    __syncthreads();
    for (int c = 0; c < 16; c++) {
        if (c < 15) loadg((c + 1) * 32);
        int bsel = c & 1;
        #pragma unroll 8
        for (int r2 = 0; r2 < 32; r2++) {
            float kd = kl[bsel][r2][d];
            ks += kd;
            const float4* vv = (const float4*)&vl[bsel][r2][g * 16];
            float4 a0 = vv[0], a1 = vv[1], a2 = vv[2], a3 = vv[3];
            kv[0]  += kd * a0.x; kv[1]  += kd * a0.y; kv[2]  += kd * a0.z; kv[3]  += kd * a0.w;
            kv[4]  += kd * a1.x; kv[5]  += kd * a1.y; kv[6]  += kd * a1.z; kv[7]  += kd * a1.w;
            kv[8]  += kd * a2.x; kv[9]  += kd * a2.y; kv[10] += kd * a2.z; kv[11] += kd * a2.w;
            kv[12] += kd * a3.x; kv[13] += kd * a3.y; kv[14] += kd * a3.z; kv[15] += kd * a3.w;
        }
        if (c < 15) storel((c + 1) & 1);
        __syncthreads();
    }
    float* dstg = kvbuf + (size_t)bh * 4160;
    #pragma unroll
    for (int j = 0; j < 16; j++)
        atomicAdd(&dstg[(g * 16 + j) * 64 + d], kv[j]);   // transposed: [e][d]
    if (g == 0) atomicAdd(&dstg[4096 + d], ks);
}

// ---------------- linear attention: apply via MFMA -------------------------
__global__ __launch_bounds__(256) void attn_apply(
    const unsigned short* __restrict__ qkv, const float* __restrict__ kvbuf,
    unsigned short* __restrict__ attnC)
{
    int blk = blockIdx.x;
    int nchunk = blk & 31;
    int bh = blk >> 5;
    int b = bh / 12, h = bh % 12;
    int n0 = nchunk * 128;
    int t = threadIdx.x;
    int lane = t & 63, wave = t >> 6;
    __shared__ __align__(16) unsigned short ql[128][72];
    __shared__ __align__(16) unsigned short Bs[80][72];

    {   // stage kvT (fp32->bf16) rows 0..63; ksum row 64; zeros 65..79
        const float* kvg = kvbuf + (size_t)bh * 4160;
        int e = t >> 2, d0 = (t & 3) * 16;
        const float4* src4 = (const float4*)(kvg + e * 64 + d0);
        #pragma unroll
        for (int i = 0; i < 4; i++) {
            float4 v = src4[i];
            unsigned long long pk = (unsigned long long)f2bf(v.x)
                | ((unsigned long long)f2bf(v.y) << 16)
                | ((unsigned long long)f2bf(v.z) << 32)
                | ((unsigned long long)f2bf(v.w) << 48);
            *(unsigned long long*)&Bs[e][d0 + i * 4] = pk;
        }
        if (t < 64) {
            Bs[64][t] = f2bf(kvg[4096 + t]);
            #pragma unroll
            for (int r = 65; r < 80; r++) Bs[r][t] = 0;
        }
    }
    {   // stage q rows (raw bf16 copy)
        int r = t >> 1, c0 = (t & 1) * 32;
        const uint4* src = (const uint4*)(qkv + (size_t)(b * 4096 + n0 + r) * 2304 + h * 64 + c0);
        uint4* dst = (uint4*)&ql[r][c0];
        #pragma unroll
        for (int i = 0; i < 4; i++) dst[i] = src[i];
    }
    __syncthreads();

    int frow = lane & 15, quad = lane >> 4;
    floatx4 acc[2][5];
    #pragma unroll
    for (int it = 0; it < 2; it++)
        #pragma unroll
        for (int jt = 0; jt < 5; jt++)
            acc[it][jt] = (floatx4){0.f, 0.f, 0.f, 0.f};

    #pragma unroll
    for (int ks = 0; ks < 2; ks++) {
        int fk = ks * 32 + quad * 8;
        short8 a0 = *(const short8*)&ql[wave * 32 + frow][fk];
        short8 a1 = *(const short8*)&ql[wave * 32 + 16 + frow][fk];
        #pragma unroll
        for (int jt = 0; jt < 5; jt++) {
            short8 bb = *(const short8*)&Bs[jt * 16 + frow][fk];
            acc[0][jt] = __builtin_amdgcn_mfma_f32_16x16x32_bf16(a0, bb, acc[0][jt], 0, 0, 0);
            acc[1][jt] = __builtin_amdgcn_mfma_f32_16x16x32_bf16(a1, bb, acc[1][jt], 0, 0, 0);
        }
    }

    #pragma unroll
    for (int it = 0; it < 2; it++) {
        #pragma unroll
        for (int rr = 0; rr < 4; rr++) {
            float nv = __shfl(acc[it][4][rr], (lane & 48));   // norm from col 0 of tile 4
            float inv = 1.0f / (nv + 1e-6f);
            int row = n0 + wave * 32 + it * 16 + quad * 4 + rr;
            size_t obase = (size_t)(b * 4096 + row) * 768 + h * 64;
            #pragma unroll
            for (int jt = 0; jt < 4; jt++)
                attnC[obase + jt * 16 + frow] = f2bf(acc[it][jt][rr] * inv);
        }
    }
}

// ---------------------------------------------------------------------------
extern "C" void kernel_launch(void* const* d_in, const int* in_sizes, int n_in,
                              void* d_out, int out_size, void* d_ws, size_t ws_size,
                              hipStream_t stream)
{
    const float* x      = (const float*)d_in[0];
    const float* w_qkv  = (const float*)d_in[1];
    const float* b_qkv  = (const float*)d_in[2];
    const float* w_proj = (const float*)d_in[3];
    const float* b_proj = (const float*)d_in[4];
    const float* g1     = (const float*)d_in[5];
    const float* be1    = (const float*)d_in[6];
    const float* g2     = (const float*)d_in[7];
    const float* be2    = (const float*)d_in[8];
    const float* w_down = (const float*)d_in[9];
    const float* b_down = (const float*)d_in[10];
    const float* w_up   = (const float*)d_in[11];
    const float* b_up   = (const float*)d_in[12];
    const float* g3     = (const float*)d_in[13];
    const float* be3    = (const float*)d_in[14];

    char* p = (char*)d_ws;
    auto take = [&](size_t b) { char* q = p; p += (b + 255) & ~(size_t)255; return q; };
    unsigned short* wtq  = (unsigned short*)take((size_t)2304 * 768 * 2);
    unsigned short* wtp  = (unsigned short*)take((size_t)768 * 768 * 2);
    unsigned short* wtd  = (unsigned short*)take((size_t)384 * 768 * 2);
    unsigned short* wtu  = (unsigned short*)take((size_t)768 * 384 * 2);
    unsigned short* bufA = (unsigned short*)take((size_t)32768 * 768 * 2);  // ln1 / attnC
    unsigned short* qkvb = (unsigned short*)take((size_t)32768 * 2304 * 2); // qkv; then r/projout/upout
    float*          kvb  = (float*)take((size_t)96 * 4160 * 4);
    unsigned short* hbuf = (unsigned short*)take((size_t)32768 * 384 * 2);
    // qkv dead after attn_apply; carve its 151 MB into three 50 MB bf16 buffers
    unsigned short* rbuf    = qkvb;
    unsigned short* projout = qkvb + (size_t)32768 * 768;
    unsigned short* upout   = qkvb + (size_t)2 * 32768 * 768;

    size_t needed = (size_t)(p - (char*)d_ws);
    if (needed > ws_size)
        fprintf(stderr, "WARNING: ws too small: need %zu have %zu\n", needed, ws_size);

    transpose_all<<<2880, 256, 0, stream>>>(w_qkv, w_proj, w_down, w_up, wtq, wtp, wtd, wtu);
    hipMemsetAsync(kvb, 0, (size_t)96 * 4160 * 4, stream);

    // ln1 = LN(x) (bf16)
    ln_kernel<true><<<32768, 384, 0, stream>>>(x, g1, be1, bufA);
    // qkv = ln1 @ Wqkv + b, elu+1 on q,k
    gemm_kernel<0><<<dim3(256, 18), 256, 0, stream>>>(bufA, wtq, b_qkv, qkvb, 32768, 768, 2304);
    // attention
    kv_accum<<<768, 256, 0, stream>>>(qkvb, kvb);
    attn_apply<<<3072, 256, 0, stream>>>(qkvb, kvb, bufA);
    // projout = attn @ Wproj + b (bf16, no residual)
    gemm_kernel<1><<<dim3(256, 6), 256, 0, stream>>>(bufA, wtp, b_proj, projout, 32768, 768, 768);
    // r = LN(x + projout) (bf16)
    add_ln_kernel<true, false><<<32768, 384, 0, stream>>>(projout, x, g2, be2, rbuf);
    // h = gelu(r @ Wdown + b) (bf16)
    gemm_kernel<2><<<dim3(256, 3), 256, 0, stream>>>(rbuf, wtd, b_down, hbuf, 32768, 768, 384);
    // upout = h @ Wup + b (bf16)
    gemm_kernel<1><<<dim3(256, 6), 256, 0, stream>>>(hbuf, wtu, b_up, upout, 32768, 384, 768);
    // out = LN(r + upout) (fp32, d_out)
    add_ln_kernel<false, true><<<32768, 384, 0, stream>>>(upout, rbuf, g3, be3, (float*)d_out);
}

// Round 4
// 686.554 us; speedup vs baseline: 1.6025x; 1.0170x over previous
//
#include <hip/hip_runtime.h>
#include <hip/hip_bf16.h>
#include <cstdio>

// ---------------------------------------------------------------------------
// DinomalyBlock forward: B=8, N=4096, C=768, H=12, D=64, BN=384
// ---------------------------------------------------------------------------

typedef __attribute__((ext_vector_type(8))) short short8;
typedef __attribute__((ext_vector_type(4))) float floatx4;

__device__ __forceinline__ float bf2f(unsigned short u) {
    return __uint_as_float(((unsigned int)u) << 16);
}
__device__ __forceinline__ unsigned short f2bf(float f) {
    __hip_bfloat16 h = __float2bfloat16(f);
    return *reinterpret_cast<unsigned short*>(&h);
}

// async global->LDS, 16B/lane; LDS dest = wave-uniform base + lane*16
__device__ __forceinline__ void async_copy16(const unsigned short* g, unsigned short* l) {
    __builtin_amdgcn_global_load_lds(
        (const __attribute__((address_space(1))) unsigned int*)g,
        (__attribute__((address_space(3))) unsigned int*)l, 16, 0, 0);
}

// ---------------- all weight transposes in one launch ----------------------
// W: [K][Nc] fp32 -> Wt: [Nc][K] bf16, 32x32 tiles
__global__ __launch_bounds__(256) void transpose_all(
    const float* __restrict__ wq, const float* __restrict__ wp,
    const float* __restrict__ wd, const float* __restrict__ wu,
    unsigned short* __restrict__ tq, unsigned short* __restrict__ tp,
    unsigned short* __restrict__ td, unsigned short* __restrict__ tu)
{
    int blk = blockIdx.x;
    const float* w; unsigned short* o; int K, Nc, tx32;
    if (blk < 1728)      { w = wq; o = tq; K = 768; Nc = 2304; tx32 = 24; }
    else if (blk < 2304) { w = wp; o = tp; K = 768; Nc = 768;  tx32 = 24; blk -= 1728; }
    else if (blk < 2592) { w = wd; o = td; K = 768; Nc = 384;  tx32 = 24; blk -= 2304; }
    else                 { w = wu; o = tu; K = 384; Nc = 768;  tx32 = 12; blk -= 2592; }
    int kb = (blk % tx32) * 32, nb = (blk / tx32) * 32;
    __shared__ float tile[32][33];
    int tx = threadIdx.x & 31, ty = threadIdx.x >> 5;   // 32x8
    #pragma unroll
    for (int i = 0; i < 32; i += 8)
        tile[ty + i][tx] = w[(size_t)(kb + ty + i) * Nc + nb + tx];
    __syncthreads();
    #pragma unroll
    for (int i = 0; i < 32; i += 8)
        o[(size_t)(nb + ty + i) * K + kb + tx] = f2bf(tile[tx][ty + i]);
}

// ---------------- LayerNorm over C=768, 384 threads ------------------------
template<bool OBF16>
__global__ __launch_bounds__(384) void ln_kernel(
    const float* __restrict__ in, const float* __restrict__ gw,
    const float* __restrict__ bw, void* __restrict__ outp)
{
    int row = blockIdx.x;
    int t = threadIdx.x;
    float2 xv = ((const float2*)(in + (size_t)row * 768))[t];
    float s = xv.x + xv.y;
    float ss = xv.x * xv.x + xv.y * xv.y;
    #pragma unroll
    for (int o = 32; o > 0; o >>= 1) {
        s += __shfl_down(s, o);
        ss += __shfl_down(ss, o);
    }
    __shared__ float red[14];
    int wave = t >> 6, lane = t & 63;
    if (lane == 0) { red[wave] = s; red[6 + wave] = ss; }
    __syncthreads();
    if (t == 0) {
        float S = 0.f, SS = 0.f;
        #pragma unroll
        for (int i = 0; i < 6; i++) { S += red[i]; SS += red[6 + i]; }
        float mu = S * (1.0f / 768.0f);
        float var = SS * (1.0f / 768.0f) - mu * mu;
        red[12] = mu;
        red[13] = rsqrtf(var + 1e-5f);
    }
    __syncthreads();
    float mu = red[12], rstd = red[13];
    float2 g = ((const float2*)gw)[t];
    float2 b = ((const float2*)bw)[t];
    float y0 = (xv.x - mu) * rstd * g.x + b.x;
    float y1 = (xv.y - mu) * rstd * g.y + b.y;
    if (OBF16) {
        unsigned int pk = (unsigned int)f2bf(y0) | ((unsigned int)f2bf(y1) << 16);
        ((unsigned int*)outp)[(size_t)row * 384 + t] = pk;
    } else {
        ((float2*)outp)[(size_t)row * 384 + t] = make_float2(y0, y1);
    }
}

// ---------------- fused residual add + LayerNorm ---------------------------
// s = bf16(y) + res ; out = LN(s)
template<bool RES_F32, bool OUT_F32>
__global__ __launch_bounds__(384) void add_ln_kernel(
    const unsigned short* __restrict__ y, const void* __restrict__ resv,
    const float* __restrict__ gw, const float* __restrict__ bw,
    void* __restrict__ outp)
{
    int row = blockIdx.x;
    int t = threadIdx.x;
    unsigned int yp = ((const unsigned int*)(y + (size_t)row * 768))[t];
    float a0 = bf2f((unsigned short)(yp & 0xffff));
    float a1 = bf2f((unsigned short)(yp >> 16));
    float r0, r1;
    if (RES_F32) {
        float2 rv = ((const float2*)((const float*)resv + (size_t)row * 768))[t];
        r0 = rv.x; r1 = rv.y;
    } else {
        unsigned int rp = ((const unsigned int*)((const unsigned short*)resv + (size_t)row * 768))[t];
        r0 = bf2f((unsigned short)(rp & 0xffff));
        r1 = bf2f((unsigned short)(rp >> 16));
    }
    float v0 = a0 + r0, v1 = a1 + r1;
    float s = v0 + v1;
    float ss = v0 * v0 + v1 * v1;
    #pragma unroll
    for (int o = 32; o > 0; o >>= 1) {
        s += __shfl_down(s, o);
        ss += __shfl_down(ss, o);
    }
    __shared__ float red[14];
    int wave = t >> 6, lane = t & 63;
    if (lane == 0) { red[wave] = s; red[6 + wave] = ss; }
    __syncthreads();
    if (t == 0) {
        float S = 0.f, SS = 0.f;
        #pragma unroll
        for (int i = 0; i < 6; i++) { S += red[i]; SS += red[6 + i]; }
        float mu = S * (1.0f / 768.0f);
        float var = SS * (1.0f / 768.0f) - mu * mu;
        red[12] = mu;
        red[13] = rsqrtf(var + 1e-5f);
    }
    __syncthreads();
    float mu = red[12], rstd = red[13];
    float2 g = ((const float2*)gw)[t];
    float2 b = ((const float2*)bw)[t];
    float y0 = (v0 - mu) * rstd * g.x + b.x;
    float y1 = (v1 - mu) * rstd * g.y + b.y;
    if (OUT_F32) {
        ((float2*)outp)[(size_t)row * 384 + t] = make_float2(y0, y1);
    } else {
        unsigned int pk = (unsigned int)f2bf(y0) | ((unsigned int)f2bf(y1) << 16);
        ((unsigned int*)outp)[(size_t)row * 384 + t] = pk;
    }
}

// ---------------- MFMA GEMM: out = A[M,K](bf16) @ Wt[Nc,K]^T + bias --------
// BK=64, XOR-swizzled LDS; grid = dim3(NCT, NRT): col-fastest dispatch so
// consecutive blocks share one A row-panel (L2/L3 locality).
// MODE 0: elu+1 on cols<1536 (qkv) | 1: plain | 2: exact GELU
template<int MODE>
__global__ __launch_bounds__(256, 4) void gemm_kernel(
    const unsigned short* __restrict__ A,
    const unsigned short* __restrict__ Wt,
    const float* __restrict__ bias,
    unsigned short* __restrict__ outp,
    int M, int K, int Nc)
{
    __shared__ __align__(16) unsigned short As[128][64];
    __shared__ __align__(16) unsigned short Bs[128][64];
    const int row0 = blockIdx.y * 128;   // slow dim
    const int col0 = blockIdx.x * 128;   // fast dim -> col-fastest dispatch
    const int t = threadIdx.x;
    const int lane = t & 63;
    const int wave = t >> 6;
    const int wm = (wave >> 1) * 64;
    const int wn = (wave & 1) * 64;
    const int frow = lane & 15;
    const int quad = lane >> 4;
    const int lrow = lane >> 3;                 // 0..7 within staging group
    const int lchunk = (lane & 7) ^ lrow;       // logical chunk this lane fetches

    floatx4 acc[4][4];
    #pragma unroll
    for (int i = 0; i < 4; i++)
        #pragma unroll
        for (int j = 0; j < 4; j++)
            acc[i][j] = (floatx4){0.f, 0.f, 0.f, 0.f};

    for (int k0 = 0; k0 < K; k0 += 64) {
        __syncthreads();   // previous iter's frag reads done
        #pragma unroll
        for (int q = 0; q < 4; q++) {
            int r = wave * 32 + q * 8 + lrow;
            async_copy16(A  + (size_t)(row0 + r) * K + k0 + lchunk * 8, &As[wave * 32 + q * 8][0]);
            async_copy16(Wt + (size_t)(col0 + r) * K + k0 + lchunk * 8, &Bs[wave * 32 + q * 8][0]);
        }
        __syncthreads();   // drains vmcnt
        #pragma unroll
        for (int ks = 0; ks < 2; ks++) {
            const int pc = ((ks * 4 + quad) ^ (frow & 7)) * 8;
            short8 af[4], bf4[4];
            #pragma unroll
            for (int i = 0; i < 4; i++) af[i] = *(const short8*)&As[wm + i * 16 + frow][pc];
            #pragma unroll
            for (int j = 0; j < 4; j++) bf4[j] = *(const short8*)&Bs[wn + j * 16 + frow][pc];
            #pragma unroll
            for (int i = 0; i < 4; i++)
                #pragma unroll
                for (int j = 0; j < 4; j++)
                    acc[i][j] = __builtin_amdgcn_mfma_f32_16x16x32_bf16(
                        af[i], bf4[j], acc[i][j], 0, 0, 0);
        }
    }

    #pragma unroll
    for (int i = 0; i < 4; i++) {
        #pragma unroll
        for (int j = 0; j < 4; j++) {
            int col = col0 + wn + j * 16 + frow;
            float bcol = bias[col];
            #pragma unroll
            for (int rr = 0; rr < 4; rr++) {
                int row = row0 + wm + i * 16 + quad * 4 + rr;
                float v = acc[i][j][rr] + bcol;
                if (MODE == 0) {
                    if (col < 1536) v = (v > 0.f) ? (v + 1.f) : expf(v);
                } else if (MODE == 2) {
                    v = 0.5f * v * (1.0f + erff(v * 0.70710678118654752f));
                }
                outp[(size_t)row * Nc + col] = f2bf(v);
            }
        }
    }
}

// ---------------- linear attention: kv accumulation ------------------------
// grid = B*H*8 (512 rows each); kvbuf[bh] 4160 fp32: [e*64+d]=kvT, [4096+d]=ksum
__global__ __launch_bounds__(256) void kv_accum(
    const unsigned short* __restrict__ qkv, float* __restrict__ kvbuf)
{
    int blk = blockIdx.x;
    int chunk = blk & 7;
    int bh = blk >> 3;
    int b = bh / 12, h = bh % 12;
    int n0 = chunk * 512;
    int t = threadIdx.x;
    int d = t & 63, g = t >> 6;
    __shared__ float kl[2][32][68];
    __shared__ float vl[2][32][68];
    float kv[16];
    #pragma unroll
    for (int j = 0; j < 16; j++) kv[j] = 0.f;
    float ks = 0.f;

    int sr = t >> 3;            // staging row 0..31
    int c16 = (t & 7) * 16;     // 0..112
    bool isk = c16 < 64;
    int cc = isk ? c16 : c16 - 64;
    const unsigned short* gbase =
        qkv + (size_t)(b * 4096 + n0 + sr) * 2304 + (isk ? 768 : 1536) + h * 64 + cc;
    uint4 r0, r1;
    auto loadg = [&](int nb) {
        const uint4* s = (const uint4*)(gbase + (size_t)nb * 2304);
        r0 = s[0]; r1 = s[1];
    };
    auto storel = [&](int buf) {
        float* dst = isk ? &kl[buf][sr][cc] : &vl[buf][sr][cc];
        const unsigned short* u0 = (const unsigned short*)&r0;
        const unsigned short* u1 = (const unsigned short*)&r1;
        #pragma unroll
        for (int i = 0; i < 8; i++) dst[i] = bf2f(u0[i]);
        #pragma unroll
        for (int i = 0; i < 8; i++) dst[8 + i] = bf2f(u1[i]);
    };

    loadg(0);
    storel(0);
    __syncthreads();
    for (int c = 0; c < 16; c++) {
        if (c < 15) loadg((c + 1) * 32);
        int bsel = c & 1;
        #pragma unroll 8
        for (int r2 = 0; r2 < 32; r2++) {
            float kd = kl[bsel][r2][d];
            ks += kd;
            const float4* vv = (const float4*)&vl[bsel][r2][g * 16];
            float4 a0 = vv[0], a1 = vv[1], a2 = vv[2], a3 = vv[3];
            kv[0]  += kd * a0.x; kv[1]  += kd * a0.y; kv[2]  += kd * a0.z; kv[3]  += kd * a0.w;
            kv[4]  += kd * a1.x; kv[5]  += kd * a1.y; kv[6]  += kd * a1.z; kv[7]  += kd * a1.w;
            kv[8]  += kd * a2.x; kv[9]  += kd * a2.y; kv[10] += kd * a2.z; kv[11] += kd * a2.w;
            kv[12] += kd * a3.x; kv[13] += kd * a3.y; kv[14] += kd * a3.z; kv[15] += kd * a3.w;
        }
        if (c < 15) storel((c + 1) & 1);
        __syncthreads();
    }
    float* dstg = kvbuf + (size_t)bh * 4160;
    #pragma unroll
    for (int j = 0; j < 16; j++)
        atomicAdd(&dstg[(g * 16 + j) * 64 + d], kv[j]);   // transposed: [e][d]
    if (g == 0) atomicAdd(&dstg[4096 + d], ks);
}

// ---------------- linear attention: apply via MFMA -------------------------
__global__ __launch_bounds__(256) void attn_apply(
    const unsigned short* __restrict__ qkv, const float* __restrict__ kvbuf,
    unsigned short* __restrict__ attnC)
{
    int blk = blockIdx.x;
    int nchunk = blk & 31;
    int bh = blk >> 5;
    int b = bh / 12, h = bh % 12;
    int n0 = nchunk * 128;
    int t = threadIdx.x;
    int lane = t & 63, wave = t >> 6;
    __shared__ __align__(16) unsigned short ql[128][72];
    __shared__ __align__(16) unsigned short Bs[80][72];

    {   // stage kvT (fp32->bf16) rows 0..63; ksum row 64; zeros 65..79
        const float* kvg = kvbuf + (size_t)bh * 4160;
        int e = t >> 2, d0 = (t & 3) * 16;
        const float4* src4 = (const float4*)(kvg + e * 64 + d0);
        #pragma unroll
        for (int i = 0; i < 4; i++) {
            float4 v = src4[i];
            unsigned long long pk = (unsigned long long)f2bf(v.x)
                | ((unsigned long long)f2bf(v.y) << 16)
                | ((unsigned long long)f2bf(v.z) << 32)
                | ((unsigned long long)f2bf(v.w) << 48);
            *(unsigned long long*)&Bs[e][d0 + i * 4] = pk;
        }
        if (t < 64) {
            Bs[64][t] = f2bf(kvg[4096 + t]);
            #pragma unroll
            for (int r = 65; r < 80; r++) Bs[r][t] = 0;
        }
    }
    {   // stage q rows (raw bf16 copy)
        int r = t >> 1, c0 = (t & 1) * 32;
        const uint4* src = (const uint4*)(qkv + (size_t)(b * 4096 + n0 + r) * 2304 + h * 64 + c0);
        uint4* dst = (uint4*)&ql[r][c0];
        #pragma unroll
        for (int i = 0; i < 4; i++) dst[i] = src[i];
    }
    __syncthreads();

    int frow = lane & 15, quad = lane >> 4;
    floatx4 acc[2][5];
    #pragma unroll
    for (int it = 0; it < 2; it++)
        #pragma unroll
        for (int jt = 0; jt < 5; jt++)
            acc[it][jt] = (floatx4){0.f, 0.f, 0.f, 0.f};

    #pragma unroll
    for (int ks = 0; ks < 2; ks++) {
        int fk = ks * 32 + quad * 8;
        short8 a0 = *(const short8*)&ql[wave * 32 + frow][fk];
        short8 a1 = *(const short8*)&ql[wave * 32 + 16 + frow][fk];
        #pragma unroll
        for (int jt = 0; jt < 5; jt++) {
            short8 bb = *(const short8*)&Bs[jt * 16 + frow][fk];
            acc[0][jt] = __builtin_amdgcn_mfma_f32_16x16x32_bf16(a0, bb, acc[0][jt], 0, 0, 0);
            acc[1][jt] = __builtin_amdgcn_mfma_f32_16x16x32_bf16(a1, bb, acc[1][jt], 0, 0, 0);
        }
    }

    #pragma unroll
    for (int it = 0; it < 2; it++) {
        #pragma unroll
        for (int rr = 0; rr < 4; rr++) {
            float nv = __shfl(acc[it][4][rr], (lane & 48));   // norm from col 0 of tile 4
            float inv = 1.0f / (nv + 1e-6f);
            int row = n0 + wave * 32 + it * 16 + quad * 4 + rr;
            size_t obase = (size_t)(b * 4096 + row) * 768 + h * 64;
            #pragma unroll
            for (int jt = 0; jt < 4; jt++)
                attnC[obase + jt * 16 + frow] = f2bf(acc[it][jt][rr] * inv);
        }
    }
}

// ---------------------------------------------------------------------------
extern "C" void kernel_launch(void* const* d_in, const int* in_sizes, int n_in,
                              void* d_out, int out_size, void* d_ws, size_t ws_size,
                              hipStream_t stream)
{
    const float* x      = (const float*)d_in[0];
    const float* w_qkv  = (const float*)d_in[1];
    const float* b_qkv  = (const float*)d_in[2];
    const float* w_proj = (const float*)d_in[3];
    const float* b_proj = (const float*)d_in[4];
    const float* g1     = (const float*)d_in[5];
    const float* be1    = (const float*)d_in[6];
    const float* g2     = (const float*)d_in[7];
    const float* be2    = (const float*)d_in[8];
    const float* w_down = (const float*)d_in[9];
    const float* b_down = (const float*)d_in[10];
    const float* w_up   = (const float*)d_in[11];
    const float* b_up   = (const float*)d_in[12];
    const float* g3     = (const float*)d_in[13];
    const float* be3    = (const float*)d_in[14];

    char* p = (char*)d_ws;
    auto take = [&](size_t b) { char* q = p; p += (b + 255) & ~(size_t)255; return q; };
    unsigned short* wtq  = (unsigned short*)take((size_t)2304 * 768 * 2);
    unsigned short* wtp  = (unsigned short*)take((size_t)768 * 768 * 2);
    unsigned short* wtd  = (unsigned short*)take((size_t)384 * 768 * 2);
    unsigned short* wtu  = (unsigned short*)take((size_t)768 * 384 * 2);
    unsigned short* bufA = (unsigned short*)take((size_t)32768 * 768 * 2);  // ln1 / attnC
    unsigned short* qkvb = (unsigned short*)take((size_t)32768 * 2304 * 2); // qkv; then r/projout/upout
    float*          kvb  = (float*)take((size_t)96 * 4160 * 4);
    unsigned short* hbuf = (unsigned short*)take((size_t)32768 * 384 * 2);
    // qkv dead after attn_apply; carve its 151 MB into three 50 MB bf16 buffers
    unsigned short* rbuf    = qkvb;
    unsigned short* projout = qkvb + (size_t)32768 * 768;
    unsigned short* upout   = qkvb + (size_t)2 * 32768 * 768;

    size_t needed = (size_t)(p - (char*)d_ws);
    if (needed > ws_size)
        fprintf(stderr, "WARNING: ws too small: need %zu have %zu\n", needed, ws_size);

    transpose_all<<<2880, 256, 0, stream>>>(w_qkv, w_proj, w_down, w_up, wtq, wtp, wtd, wtu);
    hipMemsetAsync(kvb, 0, (size_t)96 * 4160 * 4, stream);

    // ln1 = LN(x) (bf16)
    ln_kernel<true><<<32768, 384, 0, stream>>>(x, g1, be1, bufA);
    // qkv = ln1 @ Wqkv + b, elu+1 on q,k   (grid: col-fastest)
    gemm_kernel<0><<<dim3(18, 256), 256, 0, stream>>>(bufA, wtq, b_qkv, qkvb, 32768, 768, 2304);
    // attention
    kv_accum<<<768, 256, 0, stream>>>(qkvb, kvb);
    attn_apply<<<3072, 256, 0, stream>>>(qkvb, kvb, bufA);
    // projout = attn @ Wproj + b (bf16, no residual)
    gemm_kernel<1><<<dim3(6, 256), 256, 0, stream>>>(bufA, wtp, b_proj, projout, 32768, 768, 768);
    // r = LN(x + projout) (bf16)
    add_ln_kernel<true, false><<<32768, 384, 0, stream>>>(projout, x, g2, be2, rbuf);
    // h = gelu(r @ Wdown + b) (bf16)
    gemm_kernel<2><<<dim3(3, 256), 256, 0, stream>>>(rbuf, wtd, b_down, hbuf, 32768, 768, 384);
    // upout = h @ Wup + b (bf16)
    gemm_kernel<1><<<dim3(6, 256), 256, 0, stream>>>(hbuf, wtu, b_up, upout, 32768, 384, 768);
    // out = LN(r + upout) (fp32, d_out)
    add_ln_kernel<false, true><<<32768, 384, 0, stream>>>(upout, rbuf, g3, be3, (float*)d_out);
}